// Round 5
// baseline (154.415 us; speedup 1.0000x reference)
//
#include <hip/hip_runtime.h>
#include <stdint.h>

// Problem constants
//  B = 32768 samples, T_X = 4, K = 128, 64 groups x 512, out = (64,128,1,1024) fp32
typedef __attribute__((ext_vector_type(8))) short bf16x8;  // 8 bf16 in 4 VGPRs
typedef __attribute__((ext_vector_type(4))) float f32x4;

__device__ __forceinline__ unsigned short f2bf(float x) {
    union { float f; uint32_t u; } v; v.f = x;
    uint32_t r = v.u + 0x7FFFu + ((v.u >> 16) & 1u);   // RNE
    return (unsigned short)(r >> 16);
}
__device__ __forceinline__ uint32_t pack2bf(float a, float b) {
    return (uint32_t)f2bf(a) | ((uint32_t)f2bf(b) << 16);
}
__device__ __forceinline__ float bf2f(uint32_t lo) {
    union { uint32_t u; float f; } v; v.u = lo << 16; return v.f;
}
__device__ __forceinline__ float lrelu(float v) { return v > 0.f ? v : 0.01f * v; }

// ---------------------------------------------------------------------------
// K0: precompute (LDS-tiled small GEMMs, coalesced staging, split hi/lo out)
//   G[i][j]  = (1/sqrt(128)) * sum_o Wk[o,i]*Wq[o,j]             (128x128)
//   M[o][c]  = inv_sqrt2 * sum_k conv_w[o, (c>>7)*128+k]*Wv[k, c&127] (128x256)
//   blocks 0..63: G 16x16 tiles; 64..191: M 16x16 tiles; 192: BN constants
// ---------------------------------------------------------------------------
__global__ __launch_bounds__(256) void precompute_kernel(
    const float* __restrict__ Wq, const float* __restrict__ Wk,
    const float* __restrict__ Wv, const float* __restrict__ conv_w,
    const float* __restrict__ conv_b, const float* __restrict__ bn_gamma,
    const float* __restrict__ bn_beta, const float* __restrict__ bn_mean,
    const float* __restrict__ bn_var,
    unsigned short* __restrict__ Gh, unsigned short* __restrict__ Gl,
    unsigned short* __restrict__ Mh, unsigned short* __restrict__ Ml,
    float* __restrict__ scale2, float* __restrict__ bias2)
{
    __shared__ float lds0[2176];   // 128x16 pad17 (8704 B) or 16x128 pad132
    __shared__ float lds1[2176];   // 128x16 pad17
    const int tid = threadIdx.x;
    const int bid = blockIdx.x;

    if (bid == 192) {                              // constants
        if (tid < 128) {
            float sc = bn_gamma[tid] * rsqrtf(bn_var[tid] + 1e-5f);
            scale2[tid] = sc;
            bias2[tid]  = (conv_b[tid] - bn_mean[tid]) * sc + bn_beta[tid];
        }
        return;
    }

    if (bid < 64) {                                // ---- G tile (i0, j0)
        int i0 = (bid >> 3) << 4, j0 = (bid & 7) << 4;
        #pragma unroll
        for (int t = 0; t < 8; ++t) {              // stage col-tiles, 64B lines
            int e = tid + t * 256;
            int o = e >> 4, c = e & 15;
            lds0[o * 17 + c] = Wk[o * 128 + i0 + c];
            lds1[o * 17 + c] = Wq[o * 128 + j0 + c];
        }
        __syncthreads();
        int ti = tid >> 4, tj = tid & 15;
        float sum = 0.f;
        #pragma unroll 8
        for (int o = 0; o < 128; ++o) sum += lds0[o * 17 + ti] * lds1[o * 17 + tj];
        float val = sum * 0.08838834764831845f;    // 1/sqrt(128)
        unsigned short h = f2bf(val);
        int idx = (i0 + ti) * 128 + j0 + tj;
        Gh[idx] = h;
        Gl[idx] = f2bf(val - bf2f(h));
    } else {                                       // ---- M tile (o0, c0)
        int rel = bid - 64;
        int o0 = (rel >> 4) << 4, c0 = (rel & 15) << 4;
        int cw0 = (c0 >> 7) << 7, cc0 = c0 & 127;
        #pragma unroll
        for (int t = 0; t < 8; ++t) {
            int e = tid + t * 256;
            int to = e >> 7, k = e & 127;          // conv_w rows: contiguous
            lds0[to * 132 + k] = conv_w[(o0 + to) * 256 + cw0 + k];
            int kk = e >> 4, c = e & 15;           // Wv col-tile
            lds1[kk * 17 + c] = Wv[kk * 128 + cc0 + c];
        }
        __syncthreads();
        int to = tid >> 4, tc = tid & 15;
        float sum = 0.f;
        #pragma unroll 8
        for (int k = 0; k < 128; ++k) sum += lds0[to * 132 + k] * lds1[k * 17 + tc];
        float val = sum * 0.7071067811865476f;     // inv_sqrt2
        unsigned short h = f2bf(val);
        int idx = (o0 + to) * 256 + c0 + tc;
        Mh[idx] = h;
        Ml[idx] = f2bf(val - bf2f(h));
    }
}

// ---------------------------------------------------------------------------
// K1: fused attention + IDWT + conv + BN + LeakyReLU.  32 samples/block,
// 1024 blocks, LDS = 32 KB (4-5 blocks/CU).
// r5 changes vs r4: (a) y converted to split-bf16 ONCE in phase 0a (kills the
// 4x-redundant per-wave f2bf work); (b) phase 1 uses one sample per 16-lane
// quad -> shfl count 192->32 per wave, U written as b128 granules; (c) first-ks
// B-frags prefetched across barriers.
// LDS: [0,16K)  phase0: y bf16 hi [0,8K) + lo [8K,16K), A-frag layout
//               phase1+: U-low bf16 (64 rows x 256B, granule-swizzled)
//      [16K,32K) phase0b out: gbuf fp32 (32 x 128) -> phase1+: U-high bf16
// Barriers: after 0a (staged y read by all waves), after 0b (g cols cross-wave),
// after phase 1 (U rows cross-wave in phase 2).
// ---------------------------------------------------------------------------
#define AADDR(row, gi)   (((row) << 8) + ((((gi) ^ ((row) & 7))) << 4))

__global__ __launch_bounds__(256) void fused_kernel(
    const float* __restrict__ x, const float* __restrict__ y,
    const unsigned short* __restrict__ Gh, const unsigned short* __restrict__ Gl,
    const unsigned short* __restrict__ Mh, const unsigned short* __restrict__ Ml,
    const float* __restrict__ scale2, const float* __restrict__ bias2,
    float* __restrict__ out)
{
    __shared__ __align__(16) unsigned char smem[32768];
    float* gbufF = (float*)(smem + 16384);

    const int tid = threadIdx.x;
    const int w = tid >> 6;          // wave 0..3
    const int l = tid & 63;          // lane
    const int quad = l >> 4;
    const int i16 = l & 15;
    const int bid = blockIdx.x;
    const int b0 = bid * 32;

    // Prefetch phase-0b first-ks B-frags (pure global; no LDS dependence)
    const int ks0 = bid & 3;
    bf16x8 pgh[2], pgl[2];
    #pragma unroll
    for (int n = 0; n < 2; ++n) {
        int off = ((2 * w + n) * 16 + i16) * 128 + ks0 * 32 + quad * 8;
        pgh[n] = *(const bf16x8*)(Gh + off);
        pgl[n] = *(const bf16x8*)(Gl + off);
    }

    // ---- Phase 0a: stage y as split bf16 hi/lo in MFMA-A-frag layout.
    // Granule job: row=j>>4, gk=j&15 -> 8 channels [8gk,8gk+8) of y row.
    {
        const float* yb = y + (size_t)b0 * 128;
        #pragma unroll
        for (int it = 0; it < 2; ++it) {
            int j = tid + it * 256;            // 512 granules total
            int row = j >> 4, gk = j & 15;
            float4 v0 = *(const float4*)(yb + row * 128 + gk * 8);
            float4 v1 = *(const float4*)(yb + row * 128 + gk * 8 + 4);
            float f[8] = {v0.x, v0.y, v0.z, v0.w, v1.x, v1.y, v1.z, v1.w};
            uint32_t hi[4], lo[4];
            #pragma unroll
            for (int e = 0; e < 4; ++e) {
                unsigned short h0 = f2bf(f[2 * e]), h1 = f2bf(f[2 * e + 1]);
                hi[e] = (uint32_t)h0 | ((uint32_t)h1 << 16);
                lo[e] = (uint32_t)f2bf(f[2 * e] - bf2f(h0)) |
                        ((uint32_t)f2bf(f[2 * e + 1] - bf2f(h1)) << 16);
            }
            int addr = AADDR(row, gk);         // rows 0..31 -> [0,8K)
            *(uint4*)(smem + addr)        = make_uint4(hi[0], hi[1], hi[2], hi[3]);
            *(uint4*)(smem + 8192 + addr) = make_uint4(lo[0], lo[1], lo[2], lo[3]);
        }
    }
    __syncthreads();

    // ---- Phase 0b: g = Y @ G^T (split precision), column-split waves.
    // wave w: g col-blocks {2w,2w+1}, both 16-sample tiles.
    {
        f32x4 accg[2][2];    // [sample-tile rt][col-block n]
        #pragma unroll
        for (int rt = 0; rt < 2; ++rt)
            #pragma unroll
            for (int n = 0; n < 2; ++n) accg[rt][n] = (f32x4){0.f, 0.f, 0.f, 0.f};
        #pragma unroll
        for (int ks = 0; ks < 4; ++ks) {
            int ksr = (ks + bid) & 3;                    // per-block rotation
            bf16x8 ah[2], al[2];
            #pragma unroll
            for (int rt = 0; rt < 2; ++rt) {
                int row = 16 * rt + i16;
                int addr = AADDR(row, ksr * 4 + quad);
                ah[rt] = *(const bf16x8*)(smem + addr);
                al[rt] = *(const bf16x8*)(smem + 8192 + addr);
            }
            #pragma unroll
            for (int n = 0; n < 2; ++n) {
                bf16x8 bh, bl;
                if (ks == 0) { bh = pgh[n]; bl = pgl[n]; }
                else {
                    int off = ((2 * w + n) * 16 + i16) * 128 + ksr * 32 + quad * 8;
                    bh = *(const bf16x8*)(Gh + off);
                    bl = *(const bf16x8*)(Gl + off);
                }
                #pragma unroll
                for (int rt = 0; rt < 2; ++rt) {
                    accg[rt][n] = __builtin_amdgcn_mfma_f32_16x16x32_bf16(ah[rt], bh, accg[rt][n], 0, 0, 0);
                    accg[rt][n] = __builtin_amdgcn_mfma_f32_16x16x32_bf16(al[rt], bh, accg[rt][n], 0, 0, 0);
                    accg[rt][n] = __builtin_amdgcn_mfma_f32_16x16x32_bf16(ah[rt], bl, accg[rt][n], 0, 0, 0);
                }
            }
        }
        // C-frag: col = i16 (i offset), row = quad*4+r (sample) -> gbuf fp32
        #pragma unroll
        for (int n = 0; n < 2; ++n) {
            int i = (2 * w + n) * 16 + i16;
            #pragma unroll
            for (int rt = 0; rt < 2; ++rt)
                #pragma unroll
                for (int r = 0; r < 4; ++r)
                    gbufF[(16 * rt + quad * 4 + r) * 128 + i] = accg[rt][n][r];
        }
    }
    __syncthreads();   // g rows assembled from all four waves' col-blocks

    // ---- Phase 1: dots + softmax + U build. One sample per quad.
    // wave w: samples [8w,8w+8) in 2 passes of 4; lane owns channels [8*i16,+8).
    // U-low overwrites y staging (all waves done: post-0b barrier covers it);
    // U-high overwrites exactly the gbuf row this quad just read (in-wave order).
    union F8 { float4 v[2]; float f[8]; };
    #pragma unroll
    for (int pass = 0; pass < 2; ++pass) {
        int b_loc = 8 * w + pass * 4 + quad;
        const float* xb = x + (size_t)(b0 + b_loc) * 512;
        F8 X[4];
        #pragma unroll
        for (int t = 0; t < 4; ++t) {
            X[t].v[0] = *(const float4*)(xb + t * 128 + i16 * 8);
            X[t].v[1] = *(const float4*)(xb + t * 128 + i16 * 8 + 4);
        }
        float4 ga = *(const float4*)(gbufF + b_loc * 128 + i16 * 8);
        float4 gb = *(const float4*)(gbufF + b_loc * 128 + i16 * 8 + 4);
        float p[4];
        #pragma unroll
        for (int t = 0; t < 4; ++t) {
            float4 a = X[t].v[0], b = X[t].v[1];
            p[t] = a.x * ga.x + a.y * ga.y + a.z * ga.z + a.w * ga.w
                 + b.x * gb.x + b.y * gb.y + b.z * gb.z + b.w * gb.w;
        }
        #pragma unroll
        for (int off = 8; off >= 1; off >>= 1) {
            p[0] += __shfl_xor(p[0], off);
            p[1] += __shfl_xor(p[1], off);
            p[2] += __shfl_xor(p[2], off);
            p[3] += __shfl_xor(p[3], off);
        }
        float mx = fmaxf(fmaxf(p[0], p[1]), fmaxf(p[2], p[3]));
        float e0 = __expf(p[0] - mx), e1 = __expf(p[1] - mx);
        float e2 = __expf(p[2] - mx), e3 = __expf(p[3] - mx);
        float inv = 1.f / (e0 + e1 + e2 + e3);
        float w0 = e0 * inv, w1 = e1 * inv, w2 = e2 * inv, w3 = e3 * inv;
        int r0 = 2 * b_loc, r1 = r0 + 1;
        int a0 = AADDR(r0, i16), a1 = AADDR(r1, i16);
        uint32_t eL[4], oL[4], eH[4], oH[4];
        #pragma unroll
        for (int e = 0; e < 4; ++e) {
            int c0 = 2 * e, c1 = 2 * e + 1;
            eL[e] = pack2bf(w0 * X[0].f[c0] + w1 * X[1].f[c0], w0 * X[0].f[c1] + w1 * X[1].f[c1]);
            oL[e] = pack2bf(w0 * X[0].f[c0] - w1 * X[1].f[c0], w0 * X[0].f[c1] - w1 * X[1].f[c1]);
            eH[e] = pack2bf(w2 * X[2].f[c0] + w3 * X[3].f[c0], w2 * X[2].f[c1] + w3 * X[3].f[c1]);
            oH[e] = pack2bf(w2 * X[2].f[c0] - w3 * X[3].f[c0], w2 * X[2].f[c1] - w3 * X[3].f[c1]);
        }
        *(uint4*)(smem + a0)         = make_uint4(eL[0], eL[1], eL[2], eL[3]);
        *(uint4*)(smem + a1)         = make_uint4(oL[0], oL[1], oL[2], oL[3]);
        *(uint4*)(smem + 16384 + a0) = make_uint4(eH[0], eH[1], eH[2], eH[3]);
        *(uint4*)(smem + 16384 + a1) = make_uint4(oH[0], oH[1], oH[2], oH[3]);
    }

    // Prefetch phase-2 first-ks B-frags before the barrier
    const int ks0b = bid & 7;
    bf16x8 pmh[2], pml[2];
    {
        int half = ks0b >> 2, kk = ks0b & 3;
        #pragma unroll
        for (int n = 0; n < 2; ++n) {
            int off = ((2 * w + n) * 16 + i16) * 256 + half * 128 + kk * 32 + quad * 8;
            pmh[n] = *(const bf16x8*)(Mh + off);
            pml[n] = *(const bf16x8*)(Ml + off);
        }
    }
    __syncthreads();   // phase 2 reads all waves' U rows

    // ---- Phase 2: Z = U @ M^T (K=256), column-split waves: wave w owns
    // channels [32w,+32), all 4 row-blocks -> each B pair feeds 8 MFMAs.
    f32x4 acc[4][2];   // [row-block rb][col-block n]
    #pragma unroll
    for (int rb = 0; rb < 4; ++rb)
        #pragma unroll
        for (int n = 0; n < 2; ++n) acc[rb][n] = (f32x4){0.f, 0.f, 0.f, 0.f};

    #pragma unroll
    for (int ks = 0; ks < 8; ++ks) {
        int ksr = (ks + bid) & 7;                  // per-block rotation
        int half = ksr >> 2, kk = ksr & 3;
        int base = half << 14;                     // 0 (U-low) or 16384 (U-high)
        int gi = kk * 4 + quad;
        bf16x8 a[4];
        #pragma unroll
        for (int rb = 0; rb < 4; ++rb)
            a[rb] = *(const bf16x8*)(smem + base + AADDR(16 * rb + i16, gi));
        #pragma unroll
        for (int n = 0; n < 2; ++n) {
            bf16x8 bh, bl;
            if (ks == 0) { bh = pmh[n]; bl = pml[n]; }
            else {
                int off = ((2 * w + n) * 16 + i16) * 256 + half * 128 + kk * 32 + quad * 8;
                bh = *(const bf16x8*)(Mh + off);
                bl = *(const bf16x8*)(Ml + off);
            }
            #pragma unroll
            for (int rb = 0; rb < 4; ++rb) {
                acc[rb][n] = __builtin_amdgcn_mfma_f32_16x16x32_bf16(a[rb], bh, acc[rb][n], 0, 0, 0);
                acc[rb][n] = __builtin_amdgcn_mfma_f32_16x16x32_bf16(a[rb], bl, acc[rb][n], 0, 0, 0);
            }
        }
    }

    // ---- Epilogue: scale/bias/LeakyReLU, j-contiguous float4 stores
    {
        float* outp = out + (size_t)(bid >> 4) * 131072 + (bid & 15) * 64;
        #pragma unroll
        for (int n = 0; n < 2; ++n) {
            int o = (2 * w + n) * 16 + i16;
            float sc = scale2[o], bi = bias2[o];
            #pragma unroll
            for (int rb = 0; rb < 4; ++rb) {
                int jb = 16 * rb + quad * 4;
                f32x4 a = acc[rb][n];
                float4 r;
                r.x = lrelu(a[0] * sc + bi);
                r.y = lrelu(a[1] * sc + bi);
                r.z = lrelu(a[2] * sc + bi);
                r.w = lrelu(a[3] * sc + bi);
                *(float4*)(outp + (size_t)o * 1024 + jb) = r;
            }
        }
    }
}

extern "C" void kernel_launch(void* const* d_in, const int* in_sizes, int n_in,
                              void* d_out, int out_size, void* d_ws, size_t ws_size,
                              hipStream_t stream)
{
    (void)in_sizes; (void)n_in; (void)out_size; (void)ws_size;
    const float* x        = (const float*)d_in[0];
    const float* y        = (const float*)d_in[1];
    const float* Wq       = (const float*)d_in[2];
    const float* Wk       = (const float*)d_in[3];
    const float* Wv       = (const float*)d_in[4];
    const float* conv_w   = (const float*)d_in[5];
    const float* conv_b   = (const float*)d_in[6];
    const float* bn_gamma = (const float*)d_in[7];
    const float* bn_beta  = (const float*)d_in[8];
    const float* bn_mean  = (const float*)d_in[9];
    const float* bn_var   = (const float*)d_in[10];

    unsigned char* ws = (unsigned char*)d_ws;
    unsigned short* Gh = (unsigned short*)(ws);                // 32 KB
    unsigned short* Gl = (unsigned short*)(ws + 32768);        // 32 KB
    unsigned short* Mh = (unsigned short*)(ws + 65536);        // 64 KB
    unsigned short* Ml = (unsigned short*)(ws + 131072);       // 64 KB
    float* scale2      = (float*)(ws + 196608);                // 512 B
    float* bias2       = (float*)(ws + 197120);                // 512 B

    hipLaunchKernelGGL(precompute_kernel, dim3(193), dim3(256), 0, stream,
                       Wq, Wk, Wv, conv_w, conv_b, bn_gamma, bn_beta, bn_mean,
                       bn_var, Gh, Gl, Mh, Ml, scale2, bias2);
    hipLaunchKernelGGL(fused_kernel, dim3(1024), dim3(256), 0, stream,
                       x, y, Gh, Gl, Mh, Ml, scale2, bias2, (float*)d_out);
}

// Round 6
// 146.075 us; speedup vs baseline: 1.0571x; 1.0571x over previous
//
#include <hip/hip_runtime.h>
#include <stdint.h>

// Problem constants
//  B = 32768 samples, T_X = 4, K = 128, 64 groups x 512, out = (64,128,1,1024) fp32
typedef __attribute__((ext_vector_type(8))) short bf16x8;  // 8 bf16 in 4 VGPRs
typedef __attribute__((ext_vector_type(4))) float f32x4;

__device__ __forceinline__ unsigned short f2bf(float x) {
    union { float f; uint32_t u; } v; v.f = x;
    uint32_t r = v.u + 0x7FFFu + ((v.u >> 16) & 1u);   // RNE
    return (unsigned short)(r >> 16);
}
__device__ __forceinline__ uint32_t pack2bf(float a, float b) {
    return (uint32_t)f2bf(a) | ((uint32_t)f2bf(b) << 16);
}
__device__ __forceinline__ float bf2f(uint32_t lo) {
    union { uint32_t u; float f; } v; v.u = lo << 16; return v.f;
}
__device__ __forceinline__ float lrelu(float v) { return v > 0.f ? v : 0.01f * v; }

// ---------------------------------------------------------------------------
// K0: precompute (LDS-tiled small GEMMs, coalesced staging)
//   G (split hi/lo bf16): G[i][j] = (1/sqrt(128)) * sum_o Wk[o,i]*Wq[o,j]
//   M (single bf16 RNE):  M[o][c] = inv_sqrt2 * sum_k conv_w[o,(c>>7)*128+k]*Wv[k,c&127]
//   blocks 0..63: G 16x16 tiles; 64..191: M 16x16 tiles; 192: BN constants
// ---------------------------------------------------------------------------
__global__ __launch_bounds__(256) void precompute_kernel(
    const float* __restrict__ Wq, const float* __restrict__ Wk,
    const float* __restrict__ Wv, const float* __restrict__ conv_w,
    const float* __restrict__ conv_b, const float* __restrict__ bn_gamma,
    const float* __restrict__ bn_beta, const float* __restrict__ bn_mean,
    const float* __restrict__ bn_var,
    unsigned short* __restrict__ Gh, unsigned short* __restrict__ Gl,
    unsigned short* __restrict__ Mh,
    float* __restrict__ scale2, float* __restrict__ bias2)
{
    __shared__ float lds0[2176];   // 128x16 pad17 (8704 B) or 16x128 pad132
    __shared__ float lds1[2176];   // 128x16 pad17
    const int tid = threadIdx.x;
    const int bid = blockIdx.x;

    if (bid == 192) {                              // constants
        if (tid < 128) {
            float sc = bn_gamma[tid] * rsqrtf(bn_var[tid] + 1e-5f);
            scale2[tid] = sc;
            bias2[tid]  = (conv_b[tid] - bn_mean[tid]) * sc + bn_beta[tid];
        }
        return;
    }

    if (bid < 64) {                                // ---- G tile (i0, j0)
        int i0 = (bid >> 3) << 4, j0 = (bid & 7) << 4;
        #pragma unroll
        for (int t = 0; t < 8; ++t) {              // stage col-tiles, 64B lines
            int e = tid + t * 256;
            int o = e >> 4, c = e & 15;
            lds0[o * 17 + c] = Wk[o * 128 + i0 + c];
            lds1[o * 17 + c] = Wq[o * 128 + j0 + c];
        }
        __syncthreads();
        int ti = tid >> 4, tj = tid & 15;
        float sum = 0.f;
        #pragma unroll 8
        for (int o = 0; o < 128; ++o) sum += lds0[o * 17 + ti] * lds1[o * 17 + tj];
        float val = sum * 0.08838834764831845f;    // 1/sqrt(128)
        unsigned short h = f2bf(val);
        int idx = (i0 + ti) * 128 + j0 + tj;
        Gh[idx] = h;
        Gl[idx] = f2bf(val - bf2f(h));
    } else {                                       // ---- M tile (o0, c0)
        int rel = bid - 64;
        int o0 = (rel >> 4) << 4, c0 = (rel & 15) << 4;
        int cw0 = (c0 >> 7) << 7, cc0 = c0 & 127;
        #pragma unroll
        for (int t = 0; t < 8; ++t) {
            int e = tid + t * 256;
            int to = e >> 7, k = e & 127;          // conv_w rows: contiguous
            lds0[to * 132 + k] = conv_w[(o0 + to) * 256 + cw0 + k];
            int kk = e >> 4, c = e & 15;           // Wv col-tile
            lds1[kk * 17 + c] = Wv[kk * 128 + cc0 + c];
        }
        __syncthreads();
        int to = tid >> 4, tc = tid & 15;
        float sum = 0.f;
        #pragma unroll 8
        for (int k = 0; k < 128; ++k) sum += lds0[to * 132 + k] * lds1[k * 17 + tc];
        Mh[(o0 + to) * 256 + c0 + tc] = f2bf(sum * 0.7071067811865476f);
    }
}

// ---------------------------------------------------------------------------
// K1: fused attention + IDWT + conv + BN + LeakyReLU.  32 samples/block,
// 1024 blocks, LDS = 32 KB.
// r6 changes vs r5: (a) ALL 16 x dwordx4 loads hoisted to kernel entry (in
// flight through phases 0a/0b -> phase 1 is pure compute); (b) M is single
// bf16 (low-split dropped): phase-2 MFMAs 128->64/wave, B loads halved;
// (c) __launch_bounds__(256,4) pins VGPR<=128 for 4 waves/SIMD.
// LDS: [0,16K)  phase0: y bf16 hi [0,8K) + lo [8K,16K), A-frag layout
//               phase1+: U-low bf16 (64 rows x 256B, granule-swizzled)
//      [16K,32K) phase0b out: gbuf fp32 (32 x 128) -> phase1+: U-high bf16
// ---------------------------------------------------------------------------
#define AADDR(row, gi)   (((row) << 8) + ((((gi) ^ ((row) & 7))) << 4))

__global__ __launch_bounds__(256, 4) void fused_kernel(
    const float* __restrict__ x, const float* __restrict__ y,
    const unsigned short* __restrict__ Gh, const unsigned short* __restrict__ Gl,
    const unsigned short* __restrict__ Mh,
    const float* __restrict__ scale2, const float* __restrict__ bias2,
    float* __restrict__ out)
{
    __shared__ __align__(16) unsigned char smem[32768];
    float* gbufF = (float*)(smem + 16384);

    const int tid = threadIdx.x;
    const int w = tid >> 6;          // wave 0..3
    const int l = tid & 63;          // lane
    const int quad = l >> 4;
    const int i16 = l & 15;
    const int bid = blockIdx.x;
    const int b0 = bid * 32;

    // ---- Hoisted loads: all of this wave's x data (consumed in phase 1) and
    // the first-ks G B-frags. No dependences; in flight through phases 0a/0b.
    union F8 { float4 v[2]; float f[8]; };
    F8 X[2][4];                      // [pass][t], 64 VGPRs
    #pragma unroll
    for (int pass = 0; pass < 2; ++pass) {
        int b_loc = 8 * w + pass * 4 + quad;
        const float* xb = x + (size_t)(b0 + b_loc) * 512 + i16 * 8;
        #pragma unroll
        for (int t = 0; t < 4; ++t) {
            X[pass][t].v[0] = *(const float4*)(xb + t * 128);
            X[pass][t].v[1] = *(const float4*)(xb + t * 128 + 4);
        }
    }
    const int ks0 = bid & 3;
    bf16x8 pgh[2], pgl[2];
    #pragma unroll
    for (int n = 0; n < 2; ++n) {
        int off = ((2 * w + n) * 16 + i16) * 128 + ks0 * 32 + quad * 8;
        pgh[n] = *(const bf16x8*)(Gh + off);
        pgl[n] = *(const bf16x8*)(Gl + off);
    }

    // ---- Phase 0a: stage y as split bf16 hi/lo in MFMA-A-frag layout.
    {
        const float* yb = y + (size_t)b0 * 128;
        #pragma unroll
        for (int it = 0; it < 2; ++it) {
            int j = tid + it * 256;            // 512 granules total
            int row = j >> 4, gk = j & 15;
            float4 v0 = *(const float4*)(yb + row * 128 + gk * 8);
            float4 v1 = *(const float4*)(yb + row * 128 + gk * 8 + 4);
            float f[8] = {v0.x, v0.y, v0.z, v0.w, v1.x, v1.y, v1.z, v1.w};
            uint32_t hi[4], lo[4];
            #pragma unroll
            for (int e = 0; e < 4; ++e) {
                unsigned short h0 = f2bf(f[2 * e]), h1 = f2bf(f[2 * e + 1]);
                hi[e] = (uint32_t)h0 | ((uint32_t)h1 << 16);
                lo[e] = (uint32_t)f2bf(f[2 * e] - bf2f(h0)) |
                        ((uint32_t)f2bf(f[2 * e + 1] - bf2f(h1)) << 16);
            }
            int addr = AADDR(row, gk);         // rows 0..31 -> [0,8K)
            *(uint4*)(smem + addr)        = make_uint4(hi[0], hi[1], hi[2], hi[3]);
            *(uint4*)(smem + 8192 + addr) = make_uint4(lo[0], lo[1], lo[2], lo[3]);
        }
    }
    __syncthreads();

    // ---- Phase 0b: g = Y @ G^T (split precision), column-split waves.
    {
        f32x4 accg[2][2];    // [sample-tile rt][col-block n]
        #pragma unroll
        for (int rt = 0; rt < 2; ++rt)
            #pragma unroll
            for (int n = 0; n < 2; ++n) accg[rt][n] = (f32x4){0.f, 0.f, 0.f, 0.f};
        #pragma unroll
        for (int ks = 0; ks < 4; ++ks) {
            int ksr = (ks + bid) & 3;                    // per-block rotation
            bf16x8 ah[2], al[2];
            #pragma unroll
            for (int rt = 0; rt < 2; ++rt) {
                int row = 16 * rt + i16;
                int addr = AADDR(row, ksr * 4 + quad);
                ah[rt] = *(const bf16x8*)(smem + addr);
                al[rt] = *(const bf16x8*)(smem + 8192 + addr);
            }
            #pragma unroll
            for (int n = 0; n < 2; ++n) {
                bf16x8 bh, bl;
                if (ks == 0) { bh = pgh[n]; bl = pgl[n]; }
                else {
                    int off = ((2 * w + n) * 16 + i16) * 128 + ksr * 32 + quad * 8;
                    bh = *(const bf16x8*)(Gh + off);
                    bl = *(const bf16x8*)(Gl + off);
                }
                #pragma unroll
                for (int rt = 0; rt < 2; ++rt) {
                    accg[rt][n] = __builtin_amdgcn_mfma_f32_16x16x32_bf16(ah[rt], bh, accg[rt][n], 0, 0, 0);
                    accg[rt][n] = __builtin_amdgcn_mfma_f32_16x16x32_bf16(al[rt], bh, accg[rt][n], 0, 0, 0);
                    accg[rt][n] = __builtin_amdgcn_mfma_f32_16x16x32_bf16(ah[rt], bl, accg[rt][n], 0, 0, 0);
                }
            }
        }
        // C-frag: col = i16 (i offset), row = quad*4+r (sample) -> gbuf fp32
        #pragma unroll
        for (int n = 0; n < 2; ++n) {
            int i = (2 * w + n) * 16 + i16;
            #pragma unroll
            for (int rt = 0; rt < 2; ++rt)
                #pragma unroll
                for (int r = 0; r < 4; ++r)
                    gbufF[(16 * rt + quad * 4 + r) * 128 + i] = accg[rt][n][r];
        }
    }
    __syncthreads();   // g rows assembled from all four waves' col-blocks

    // ---- Phase 1: dots + softmax + U build. One sample per quad, x already
    // in registers. wave w: samples [8w,8w+8); lane owns channels [8*i16,+8).
    #pragma unroll
    for (int pass = 0; pass < 2; ++pass) {
        int b_loc = 8 * w + pass * 4 + quad;
        float4 ga = *(const float4*)(gbufF + b_loc * 128 + i16 * 8);
        float4 gb = *(const float4*)(gbufF + b_loc * 128 + i16 * 8 + 4);
        float p[4];
        #pragma unroll
        for (int t = 0; t < 4; ++t) {
            float4 a = X[pass][t].v[0], b = X[pass][t].v[1];
            p[t] = a.x * ga.x + a.y * ga.y + a.z * ga.z + a.w * ga.w
                 + b.x * gb.x + b.y * gb.y + b.z * gb.z + b.w * gb.w;
        }
        #pragma unroll
        for (int off = 8; off >= 1; off >>= 1) {
            p[0] += __shfl_xor(p[0], off);
            p[1] += __shfl_xor(p[1], off);
            p[2] += __shfl_xor(p[2], off);
            p[3] += __shfl_xor(p[3], off);
        }
        float mx = fmaxf(fmaxf(p[0], p[1]), fmaxf(p[2], p[3]));
        float e0 = __expf(p[0] - mx), e1 = __expf(p[1] - mx);
        float e2 = __expf(p[2] - mx), e3 = __expf(p[3] - mx);
        float inv = 1.f / (e0 + e1 + e2 + e3);
        float w0 = e0 * inv, w1 = e1 * inv, w2 = e2 * inv, w3 = e3 * inv;
        int r0 = 2 * b_loc, r1 = r0 + 1;
        int a0 = AADDR(r0, i16), a1 = AADDR(r1, i16);
        uint32_t eL[4], oL[4], eH[4], oH[4];
        #pragma unroll
        for (int e = 0; e < 4; ++e) {
            int c0 = 2 * e, c1 = 2 * e + 1;
            eL[e] = pack2bf(w0 * X[pass][0].f[c0] + w1 * X[pass][1].f[c0], w0 * X[pass][0].f[c1] + w1 * X[pass][1].f[c1]);
            oL[e] = pack2bf(w0 * X[pass][0].f[c0] - w1 * X[pass][1].f[c0], w0 * X[pass][0].f[c1] - w1 * X[pass][1].f[c1]);
            eH[e] = pack2bf(w2 * X[pass][2].f[c0] + w3 * X[pass][3].f[c0], w2 * X[pass][2].f[c1] + w3 * X[pass][3].f[c1]);
            oH[e] = pack2bf(w2 * X[pass][2].f[c0] - w3 * X[pass][3].f[c0], w2 * X[pass][2].f[c1] - w3 * X[pass][3].f[c1]);
        }
        *(uint4*)(smem + a0)         = make_uint4(eL[0], eL[1], eL[2], eL[3]);
        *(uint4*)(smem + a1)         = make_uint4(oL[0], oL[1], oL[2], oL[3]);
        *(uint4*)(smem + 16384 + a0) = make_uint4(eH[0], eH[1], eH[2], eH[3]);
        *(uint4*)(smem + 16384 + a1) = make_uint4(oH[0], oH[1], oH[2], oH[3]);
    }

    // Prefetch phase-2 first-ks B-frags before the barrier
    const int ks0b = bid & 7;
    bf16x8 pmh[2];
    {
        int half = ks0b >> 2, kk = ks0b & 3;
        #pragma unroll
        for (int n = 0; n < 2; ++n)
            pmh[n] = *(const bf16x8*)(Mh + ((2 * w + n) * 16 + i16) * 256 + half * 128 + kk * 32 + quad * 8);
    }
    __syncthreads();   // phase 2 reads all waves' U rows

    // ---- Phase 2: Z = U @ M^T (K=256), single-bf16 M, column-split waves:
    // wave w owns channels [32w,+32), all 4 row-blocks -> B reuse = 4 MFMAs.
    f32x4 acc[4][2];   // [row-block rb][col-block n]
    #pragma unroll
    for (int rb = 0; rb < 4; ++rb)
        #pragma unroll
        for (int n = 0; n < 2; ++n) acc[rb][n] = (f32x4){0.f, 0.f, 0.f, 0.f};

    #pragma unroll
    for (int ks = 0; ks < 8; ++ks) {
        int ksr = (ks + bid) & 7;                  // per-block rotation
        int half = ksr >> 2, kk = ksr & 3;
        int base = half << 14;                     // 0 (U-low) or 16384 (U-high)
        int gi = kk * 4 + quad;
        bf16x8 a[4];
        #pragma unroll
        for (int rb = 0; rb < 4; ++rb)
            a[rb] = *(const bf16x8*)(smem + base + AADDR(16 * rb + i16, gi));
        #pragma unroll
        for (int n = 0; n < 2; ++n) {
            bf16x8 bh;
            if (ks == 0) bh = pmh[n];
            else bh = *(const bf16x8*)(Mh + ((2 * w + n) * 16 + i16) * 256 + half * 128 + kk * 32 + quad * 8);
            #pragma unroll
            for (int rb = 0; rb < 4; ++rb)
                acc[rb][n] = __builtin_amdgcn_mfma_f32_16x16x32_bf16(a[rb], bh, acc[rb][n], 0, 0, 0);
        }
    }

    // ---- Epilogue: scale/bias/LeakyReLU, j-contiguous float4 stores
    {
        float* outp = out + (size_t)(bid >> 4) * 131072 + (bid & 15) * 64;
        #pragma unroll
        for (int n = 0; n < 2; ++n) {
            int o = (2 * w + n) * 16 + i16;
            float sc = scale2[o], bi = bias2[o];
            #pragma unroll
            for (int rb = 0; rb < 4; ++rb) {
                int jb = 16 * rb + quad * 4;
                f32x4 a = acc[rb][n];
                float4 r;
                r.x = lrelu(a[0] * sc + bi);
                r.y = lrelu(a[1] * sc + bi);
                r.z = lrelu(a[2] * sc + bi);
                r.w = lrelu(a[3] * sc + bi);
                *(float4*)(outp + (size_t)o * 1024 + jb) = r;
            }
        }
    }
}

extern "C" void kernel_launch(void* const* d_in, const int* in_sizes, int n_in,
                              void* d_out, int out_size, void* d_ws, size_t ws_size,
                              hipStream_t stream)
{
    (void)in_sizes; (void)n_in; (void)out_size; (void)ws_size;
    const float* x        = (const float*)d_in[0];
    const float* y        = (const float*)d_in[1];
    const float* Wq       = (const float*)d_in[2];
    const float* Wk       = (const float*)d_in[3];
    const float* Wv       = (const float*)d_in[4];
    const float* conv_w   = (const float*)d_in[5];
    const float* conv_b   = (const float*)d_in[6];
    const float* bn_gamma = (const float*)d_in[7];
    const float* bn_beta  = (const float*)d_in[8];
    const float* bn_mean  = (const float*)d_in[9];
    const float* bn_var   = (const float*)d_in[10];

    unsigned char* ws = (unsigned char*)d_ws;
    unsigned short* Gh = (unsigned short*)(ws);                // 32 KB
    unsigned short* Gl = (unsigned short*)(ws + 32768);        // 32 KB
    unsigned short* Mh = (unsigned short*)(ws + 65536);        // 64 KB
    float* scale2      = (float*)(ws + 131072);                // 512 B
    float* bias2       = (float*)(ws + 131584);                // 512 B

    hipLaunchKernelGGL(precompute_kernel, dim3(193), dim3(256), 0, stream,
                       Wq, Wk, Wv, conv_w, conv_b, bn_gamma, bn_beta, bn_mean,
                       bn_var, Gh, Gl, Mh, scale2, bias2);
    hipLaunchKernelGGL(fused_kernel, dim3(1024), dim3(256), 0, stream,
                       x, y, Gh, Gl, Mh, scale2, bias2, (float*)d_out);
}